// Round 1
// baseline (382.501 us; speedup 1.0000x reference)
//
#include <hip/hip_runtime.h>
#include <hip/hip_bf16.h>
#include <cmath>

#define S_LEN 2048
#define D_DIM 64
#define BM 64
#define BN 64
#define LDP 72          // padded LDS row stride in bf16 elements (144 B)
#define NKT (S_LEN / BN)

typedef float f32x4 __attribute__((ext_vector_type(4)));
typedef short s16x8 __attribute__((ext_vector_type(8)));

__device__ __forceinline__ unsigned short f2b(float x) {
  union { float f; unsigned int u; } un; un.f = x;
  unsigned int u = un.u;
  unsigned int r = (u + 0x7FFF + ((u >> 16) & 1)) >> 16;  // RNE
  return (unsigned short)r;
}

__global__ __launch_bounds__(256) void bsattn_kernel(
    const float* __restrict__ Qg_, const float* __restrict__ Kg_,
    const float* __restrict__ Vg_, float* __restrict__ outg,
    float* __restrict__ attng) {
  __shared__ __align__(16) unsigned short Ql[BM * LDP];
  __shared__ __align__(16) unsigned short Kl[BN * LDP];
  __shared__ __align__(16) unsigned short Vt[D_DIM * LDP];  // V transposed: [d][j]
  __shared__ __align__(16) unsigned short Pl[BM * LDP];

  const int tid = threadIdx.x;
  const int w  = tid >> 6;
  const int l  = tid & 63;
  const int lr = l & 15;
  const int lh = l >> 4;
  const int rt = blockIdx.x;   // row tile (== block index, BM == BLOCK_SIZE)
  const int bh = blockIdx.y;   // b*H + h
  const int row0 = rt * BM;

  const float* Qg = Qg_ + (size_t)bh * S_LEN * D_DIM;
  const float* Kg = Kg_ + (size_t)bh * S_LEN * D_DIM;
  const float* Vg = Vg_ + (size_t)bh * S_LEN * D_DIM;
  float* outp  = outg  + (size_t)bh * S_LEN * D_DIM;
  float* attnp = attng + (size_t)bh * S_LEN * S_LEN;

  // ---- stage Q tile (64x64 f32 -> bf16) ----
  for (int it = 0; it < 4; ++it) {
    int lin = it * 256 + tid;
    int r = lin >> 4;
    int c = (lin & 15) << 2;
    const float4 v = *(const float4*)(Qg + (size_t)(row0 + r) * D_DIM + c);
    ushort4 b; b.x = f2b(v.x); b.y = f2b(v.y); b.z = f2b(v.z); b.w = f2b(v.w);
    *(ushort4*)&Ql[r * LDP + c] = b;
  }
  __syncthreads();

  // Q fragments for this wave's 16 rows (A-frag: row = lr, k = lh*8.. )
  const s16x8 qf0 = *(const s16x8*)&Ql[(w * 16 + lr) * LDP + lh * 8];
  const s16x8 qf1 = *(const s16x8*)&Ql[(w * 16 + lr) * LDP + 32 + lh * 8];

  float m_run[4] = {-1e30f, -1e30f, -1e30f, -1e30f};
  float l_run[4] = {0.f, 0.f, 0.f, 0.f};

  // ======== pass 1: row max + denom (online, per-lane then merged) ========
  for (int kt = 0; kt < NKT; ++kt) {
    if (kt == rt) continue;  // own block: fully masked, contributes nothing
    __syncthreads();
    const float* Kt = Kg + (size_t)kt * BN * D_DIM;
    for (int it = 0; it < 4; ++it) {
      int lin = it * 256 + tid;
      int r = lin >> 4;
      int c = (lin & 15) << 2;
      const float4 v = *(const float4*)(Kt + r * D_DIM + c);
      ushort4 b; b.x = f2b(v.x); b.y = f2b(v.y); b.z = f2b(v.z); b.w = f2b(v.w);
      *(ushort4*)&Kl[r * LDP + c] = b;
    }
    __syncthreads();

    f32x4 acc[4];
#pragma unroll
    for (int j16 = 0; j16 < 4; ++j16) {
      f32x4 a = {0.f, 0.f, 0.f, 0.f};
      s16x8 kf0 = *(const s16x8*)&Kl[(j16 * 16 + lr) * LDP + lh * 8];
      a = __builtin_amdgcn_mfma_f32_16x16x32_bf16(qf0, kf0, a, 0, 0, 0);
      s16x8 kf1 = *(const s16x8*)&Kl[(j16 * 16 + lr) * LDP + 32 + lh * 8];
      a = __builtin_amdgcn_mfma_f32_16x16x32_bf16(qf1, kf1, a, 0, 0, 0);
      acc[j16] = a;
    }
#pragma unroll
    for (int r = 0; r < 4; ++r) {
      float s0 = acc[0][r] * 0.125f;
      if (lr == 0) s0 = -INFINITY;          // j%64==0 head column
      float s1 = acc[1][r] * 0.125f;
      float s2 = acc[2][r] * 0.125f;
      float s3 = acc[3][r] * 0.125f;
      float tm = fmaxf(fmaxf(s0, s1), fmaxf(s2, s3));
      float mn = fmaxf(m_run[r], tm);
      float sc = __expf(m_run[r] - mn);
      l_run[r] = l_run[r] * sc + __expf(s0 - mn) + __expf(s1 - mn) +
                 __expf(s2 - mn) + __expf(s3 - mn);
      m_run[r] = mn;
    }
  }
  // merge (m,l) across the 16 lanes sharing the same rows
#pragma unroll
  for (int off = 8; off >= 1; off >>= 1) {
#pragma unroll
    for (int r = 0; r < 4; ++r) {
      float mo = __shfl_xor(m_run[r], off);
      float lo = __shfl_xor(l_run[r], off);
      float mn = fmaxf(m_run[r], mo);
      l_run[r] = l_run[r] * __expf(m_run[r] - mn) + lo * __expf(mo - mn);
      m_run[r] = mn;
    }
  }
  float invl[4];
#pragma unroll
  for (int r = 0; r < 4; ++r) invl[r] = 1.0f / l_run[r];

  // ======== pass 2: attn write + PV ========
  f32x4 oacc[4];
#pragma unroll
  for (int d16 = 0; d16 < 4; ++d16) oacc[d16] = (f32x4){0.f, 0.f, 0.f, 0.f};

  for (int kt = 0; kt < NKT; ++kt) {
    if (kt == rt) {
      // fully-masked tile: attn = 0
      for (int it = 0; it < 4; ++it) {
        int lin = it * 256 + tid;
        int r = lin >> 4;
        int c = (lin & 15) << 2;
        float4 z = {0.f, 0.f, 0.f, 0.f};
        *(float4*)(attnp + (size_t)(row0 + r) * S_LEN + kt * BN + c) = z;
      }
      continue;
    }
    __syncthreads();
    const float* Kt  = Kg + (size_t)kt * BN * D_DIM;
    const float* Vtg = Vg + (size_t)kt * BN * D_DIM;
    for (int it = 0; it < 4; ++it) {
      int lin = it * 256 + tid;
      int r = lin >> 4;
      int c = (lin & 15) << 2;
      const float4 v = *(const float4*)(Kt + r * D_DIM + c);
      ushort4 b; b.x = f2b(v.x); b.y = f2b(v.y); b.z = f2b(v.z); b.w = f2b(v.w);
      *(ushort4*)&Kl[r * LDP + c] = b;
      const float4 vv = *(const float4*)(Vtg + r * D_DIM + c);
      Vt[(c + 0) * LDP + r] = f2b(vv.x);
      Vt[(c + 1) * LDP + r] = f2b(vv.y);
      Vt[(c + 2) * LDP + r] = f2b(vv.z);
      Vt[(c + 3) * LDP + r] = f2b(vv.w);
    }
    __syncthreads();

    f32x4 acc[4];
#pragma unroll
    for (int j16 = 0; j16 < 4; ++j16) {
      f32x4 a = {0.f, 0.f, 0.f, 0.f};
      s16x8 kf0 = *(const s16x8*)&Kl[(j16 * 16 + lr) * LDP + lh * 8];
      a = __builtin_amdgcn_mfma_f32_16x16x32_bf16(qf0, kf0, a, 0, 0, 0);
      s16x8 kf1 = *(const s16x8*)&Kl[(j16 * 16 + lr) * LDP + 32 + lh * 8];
      a = __builtin_amdgcn_mfma_f32_16x16x32_bf16(qf1, kf1, a, 0, 0, 0);
      acc[j16] = a;
    }
#pragma unroll
    for (int j16 = 0; j16 < 4; ++j16) {
#pragma unroll
      for (int r = 0; r < 4; ++r) {
        float s = acc[j16][r] * 0.125f;
        if (j16 == 0 && lr == 0) s = -INFINITY;
        int irow = w * 16 + lh * 4 + r;
        float p = __expf(s - m_run[r]) * invl[r];
        attnp[(size_t)(row0 + irow) * S_LEN + kt * BN + j16 * 16 + lr] = p;
        Pl[irow * LDP + j16 * 16 + lr] = f2b(p);
      }
    }
    __syncthreads();
#pragma unroll
    for (int ks = 0; ks < 2; ++ks) {
      s16x8 pf = *(const s16x8*)&Pl[(w * 16 + lr) * LDP + ks * 32 + lh * 8];
#pragma unroll
      for (int d16 = 0; d16 < 4; ++d16) {
        s16x8 vf = *(const s16x8*)&Vt[(d16 * 16 + lr) * LDP + ks * 32 + lh * 8];
        oacc[d16] = __builtin_amdgcn_mfma_f32_16x16x32_bf16(pf, vf, oacc[d16], 0, 0, 0);
      }
    }
  }

#pragma unroll
  for (int d16 = 0; d16 < 4; ++d16) {
#pragma unroll
    for (int r = 0; r < 4; ++r) {
      int irow = w * 16 + lh * 4 + r;
      outp[(size_t)(row0 + irow) * D_DIM + d16 * 16 + lr] = oacc[d16][r];
    }
  }
}

__global__ __launch_bounds__(256) void mask_kernel(float* __restrict__ M) {
  int idx = blockIdx.x * 256 + threadIdx.x;  // one float4 each, S*S/4 total
  int i  = idx >> 9;            // row (S/4 = 512 float4 per row)
  int c4 = (idx & 511) << 2;    // starting col
  int iblk = i >> 6;
  int jblk = c4 >> 6;
  bool same = (jblk == iblk);
  float4 v;
  v.x = (same || ((c4 & 63) == 0)) ? 1.f : 0.f;
  v.y = same ? 1.f : 0.f;
  v.z = same ? 1.f : 0.f;
  v.w = same ? 1.f : 0.f;
  *(float4*)(M + (size_t)idx * 4) = v;
}

extern "C" void kernel_launch(void* const* d_in, const int* in_sizes, int n_in,
                              void* d_out, int out_size, void* d_ws, size_t ws_size,
                              hipStream_t stream) {
  const float* Q = (const float*)d_in[0];
  const float* K = (const float*)d_in[1];
  const float* V = (const float*)d_in[2];
  float* out  = (float*)d_out;
  float* attn = out + (size_t)2 * 16 * 2048 * 64;
  float* M    = attn + (size_t)2 * 16 * 2048 * 2048;

  dim3 grid(S_LEN / BM, 2 * 16);  // (row tiles, B*H)
  bsattn_kernel<<<grid, 256, 0, stream>>>(Q, K, V, out, attn);
  mask_kernel<<<(S_LEN * S_LEN / 4) / 256, 256, 0, stream>>>(M);
}